// Round 1
// baseline (1551.011 us; speedup 1.0000x reference)
//
#include <hip/hip_runtime.h>

typedef __bf16 bf16_t;
typedef bf16_t bf16x8 __attribute__((ext_vector_type(8)));
typedef bf16_t bf16x4 __attribute__((ext_vector_type(4)));
typedef float  f32x4  __attribute__((ext_vector_type(4)));

#define DEVFN __device__ __forceinline__

constexpr int BATCH = 256;
constexpr int DDIM  = 512;
constexpr int HDIM  = 2048;
constexpr int MNODE = 64;   // Chebyshev-Lobatto nodes
constexpr int NC    = 32;   // Chebyshev coefficients
constexpr int NITER = 12;
constexpr int PT    = 10;
constexpr int ROWS  = BATCH * MNODE;  // 16384 GEMM rows

DEVFN float fast_tanh(float x) {
  // tanh(x) = 1 - 2/(exp(2x)+1); exp2-based, saturates correctly at +-inf.
  float e = __builtin_amdgcn_exp2f(x * 2.8853900817779268f);
  return 1.0f - 2.0f * __builtin_amdgcn_rcpf(e + 1.0f);
}

DEVFN void gload_lds16(const void* g, void* l) {
  // async global->LDS, 16B/lane; LDS dest = wave-uniform base + lane*16
  __builtin_amdgcn_global_load_lds(
      (__attribute__((address_space(1))) void*)(g),
      (__attribute__((address_space(3))) void*)(l), 16, 0, 0);
}

DEVFN f32x4 mfma16(bf16x8 a, bf16x8 b, f32x4 c) {
  return __builtin_amdgcn_mfma_f32_16x16x32_bf16(a, b, c, 0, 0, 0);
}

// ---------------------------------------------------------------------------
// Prep: build Kmat[64][64] and Tmat[16][64] (bf16) from the fixed Chebyshev
// operators.  X_next = Kmat @ F_b + y0 ;  traj_p = Tmat @ F_b + y0.
// ---------------------------------------------------------------------------
__global__ __launch_bounds__(256) void prep_matrices(
    const float* __restrict__ tspan, bf16_t* __restrict__ Kmat,
    bf16_t* __restrict__ Tmat) {
  __shared__ float sphi[NC][MNODE];
  __shared__ float spsi[NC][MNODE];
  __shared__ float sA32[NC][NC];
  __shared__ float sAP[NC][MNODE];
  __shared__ float sphis[NC][PT];

  const int tid = threadIdx.x;
  const float t0 = tspan[0], t1 = tspan[PT - 1];
  const float half = 0.5f * (t1 - t0);
  const float pi = 3.14159265358979323846f;

  for (int i = tid; i < NC * MNODE; i += 256) {
    int n = i >> 6, m = i & 63;
    float th = pi * (float)m / 63.0f;
    float ph = cosf((float)n * th);
    sphi[n][m] = ph;
    float w = (m == 0 || m == 63) ? 0.5f : 1.0f;
    spsi[n][m] = ph * w * (2.0f / 63.0f) * (n == 0 ? 0.5f : 1.0f);
  }
  // A32 = P * Dmat : c -> B  (antiderivative + y0-pinning structure)
  for (int i = tid; i < NC * NC; i += 256) {
    int j = i >> 5, q = i & 31;
    float v = 0.f;
    for (int k = 1; k < NC; ++k) {
      float dk = half / (2.0f * (float)k);
      float dval = 0.f;
      if (q == k - 1) dval += dk;
      if (q == k + 1) dval -= dk;
      float pj = (j == 0) ? ((k & 1) ? 1.0f : -1.0f) : ((j == k) ? 1.0f : 0.0f);
      v += pj * dval;
    }
    sA32[j][q] = v;
  }
  for (int i = tid; i < NC * PT; i += 256) {
    int n = i / PT, p = i % PT;
    float tau = -1.0f + 2.0f * (tspan[p] - t0) / (t1 - t0);
    tau = fminf(1.0f, fmaxf(-1.0f, tau));
    sphis[n][p] = cosf((float)n * acosf(tau));
  }
  __syncthreads();
  for (int i = tid; i < NC * MNODE; i += 256) {
    int n = i >> 6, m = i & 63;
    float v = 0.f;
    for (int q = 0; q < NC; ++q) v += sA32[n][q] * spsi[q][m];
    sAP[n][m] = v;
  }
  __syncthreads();
  for (int i = tid; i < MNODE * MNODE; i += 256) {
    int m = i >> 6, mp = i & 63;
    float v = 0.f;
    for (int n = 0; n < NC; ++n) v += sphi[n][m] * sAP[n][mp];
    Kmat[i] = (bf16_t)v;
  }
  for (int i = tid; i < 16 * MNODE; i += 256) {
    int p = i >> 6, mp = i & 63;
    float v = 0.f;
    if (p < PT) {
      for (int n = 0; n < NC; ++n) v += sphis[n][p] * sAP[n][mp];
    }
    Tmat[i] = (bf16_t)v;
  }
}

// Transpose f32 [R][C] -> bf16 [C][R]
__global__ void transpose_bf16(const float* __restrict__ src,
                               bf16_t* __restrict__ dst, int R, int C) {
  __shared__ float tile[32][33];
  const int bx = blockIdx.x * 32, by = blockIdx.y * 32;
  const int tx = threadIdx.x, ty = threadIdx.y;
#pragma unroll
  for (int i = 0; i < 32; i += 8)
    tile[ty + i][tx] = src[(size_t)(by + ty + i) * C + (bx + tx)];
  __syncthreads();
#pragma unroll
  for (int i = 0; i < 32; i += 8)
    dst[(size_t)(bx + ty + i) * R + (by + tx)] = (bf16_t)tile[tx][ty + i];
}

// X[(b*64+m)*512+d] = bf16(y0[b*512+d])  (constant initial trajectory)
__global__ void init_X(const float* __restrict__ y0, bf16_t* __restrict__ X) {
  size_t i = (size_t)blockIdx.x * 256 + threadIdx.x;  // < ROWS*DDIM
  int d = (int)(i & 511);
  int row = (int)(i >> 9);
  int b = row >> 6;
  X[i] = (bf16_t)y0[((size_t)b << 9) + d];
}

// ---------------------------------------------------------------------------
// Main MFMA GEMM, m97 structure: 128x128 tile, BK=32, 4 waves x (64x64),
// global_load_lds(16B) staging, 2-barrier K loop.
// A: [Mr][K] bf16 row-major.  Bt: [Nc][K] bf16 row-major (B transposed).
// TRANS_OUT=false: C[row][col] = bf16(tanh?(acc + bias[col]))  (row-major, Nc)
// TRANS_OUT=true : C[((b*Nc)+col)*64 + m] = bf16(acc + bias[col]), b=row/64
// ---------------------------------------------------------------------------
template <bool TANH, bool TRANS_OUT>
__global__ __launch_bounds__(256) void gemm_bt(
    const bf16_t* __restrict__ A, const bf16_t* __restrict__ Bt,
    const float* __restrict__ bias, bf16_t* __restrict__ C, int Nc, int K) {
  constexpr int BK = 32;
  __shared__ alignas(16) bf16_t As[128 * BK];  // [128 rows][32 k]
  __shared__ alignas(16) bf16_t Bs[128 * BK];  // [128 cols][32 k]

  const int tid = threadIdx.x;
  const int wid = tid >> 6;
  const int lane = tid & 63;
  const int lr = lane & 15, lg = lane >> 4;
  const int row0 = blockIdx.y * 128;
  const int col0 = blockIdx.x * 128;
  const int wr = (wid >> 1) * 64;
  const int wc = (wid & 1) * 64;

  // staging: wave w loads chunks {2w,2w+1} of each 8KB tile (1KB per chunk)
  const int c0 = wid * 2;
  const int crow = lane >> 2;          // 0..15 row within chunk
  const int kb = (lane & 3) * 8;       // k element offset
  const bf16_t* gA = A + (size_t)(row0 + c0 * 16 + crow) * K + kb;
  const bf16_t* gB = Bt + (size_t)(col0 + c0 * 16 + crow) * K + kb;
  char* lA = (char*)As + c0 * 1024;
  char* lB = (char*)Bs + c0 * 1024;

  const f32x4 fz = {0.f, 0.f, 0.f, 0.f};
  f32x4 acc[4][4];
#pragma unroll
  for (int i = 0; i < 4; ++i)
#pragma unroll
    for (int j = 0; j < 4; ++j) acc[i][j] = fz;

  const int nk = K / BK;
  gload_lds16(gA, lA);
  gload_lds16(gA + (size_t)16 * K, lA + 1024);
  gload_lds16(gB, lB);
  gload_lds16(gB + (size_t)16 * K, lB + 1024);

  for (int ks = 0; ks < nk; ++ks) {
    __syncthreads();  // staged data visible (compiler drains vmcnt)
    const bf16x8* Ap = (const bf16x8*)As;
    const bf16x8* Bp = (const bf16x8*)Bs;
    bf16x8 af[4], bfr[4];
#pragma unroll
    for (int mi = 0; mi < 4; ++mi) af[mi] = Ap[(wr + mi * 16 + lr) * 4 + lg];
#pragma unroll
    for (int ni = 0; ni < 4; ++ni) bfr[ni] = Bp[(wc + ni * 16 + lr) * 4 + lg];
#pragma unroll
    for (int mi = 0; mi < 4; ++mi)
#pragma unroll
      for (int ni = 0; ni < 4; ++ni)
        acc[mi][ni] = mfma16(af[mi], bfr[ni], acc[mi][ni]);
    __syncthreads();  // all reads done before overwrite
    if (ks + 1 < nk) {
      const bf16_t* gA2 = gA + (size_t)(ks + 1) * BK;
      const bf16_t* gB2 = gB + (size_t)(ks + 1) * BK;
      gload_lds16(gA2, lA);
      gload_lds16(gA2 + (size_t)16 * K, lA + 1024);
      gload_lds16(gB2, lB);
      gload_lds16(gB2 + (size_t)16 * K, lB + 1024);
    }
  }

#pragma unroll
  for (int ni = 0; ni < 4; ++ni) {
    const int col = col0 + wc + ni * 16 + lr;
    const float bv = bias[col];
#pragma unroll
    for (int mi = 0; mi < 4; ++mi) {
      if constexpr (TRANS_OUT) {
        const int rowbase = row0 + wr + mi * 16 + lg * 4;
        const int b = rowbase >> 6;
        const int m0 = rowbase & 63;
        bf16x4 pack;
#pragma unroll
        for (int r = 0; r < 4; ++r) pack[r] = (bf16_t)(acc[mi][ni][r] + bv);
        *(bf16x4*)(C + ((size_t)b * Nc + col) * 64 + m0) = pack;
      } else {
#pragma unroll
        for (int r = 0; r < 4; ++r) {
          const int row = row0 + wr + mi * 16 + lg * 4 + r;
          float v = acc[mi][ni][r] + bv;
          if constexpr (TANH) v = fast_tanh(v);
          C[(size_t)row * Nc + col] = (bf16_t)v;
        }
      }
    }
  }
}

// ---------------------------------------------------------------------------
// X[b, m, :] = Kmat[64x64] @ Ft[b, :, :]  + y0[b,:]   (one K-block, K=64)
// Ft layout: [(b*512+d)][64 m]  -> contiguous 16KB tile per (b, 128 d)
// ---------------------------------------------------------------------------
__global__ __launch_bounds__(256) void evalK(
    const bf16_t* __restrict__ Km, const bf16_t* __restrict__ Ft,
    const float* __restrict__ y0, bf16_t* __restrict__ X) {
  __shared__ alignas(16) bf16_t As[64 * 64];   // Kmat
  __shared__ alignas(16) bf16_t Bs[128 * 64];  // Ft tile [128 d][64 m]
  const int tid = threadIdx.x, wid = tid >> 6, lane = tid & 63;
  const int lr = lane & 15, lg = lane >> 4;
  const int b = blockIdx.y;
  const int d0 = blockIdx.x * 128;

  {
    const char* gK = (const char*)Km;
    const int c = wid * 2;
    gload_lds16(gK + c * 1024 + lane * 16, (char*)As + c * 1024);
    gload_lds16(gK + (c + 1) * 1024 + lane * 16, (char*)As + (c + 1) * 1024);
    const char* gF = (const char*)(Ft + ((size_t)b * 512 + d0) * 64);
    for (int c2 = wid * 4; c2 < wid * 4 + 4; ++c2)
      gload_lds16(gF + c2 * 1024 + lane * 16, (char*)Bs + c2 * 1024);
  }
  __syncthreads();

  const int wc = wid * 32;
  const f32x4 fz = {0.f, 0.f, 0.f, 0.f};
  f32x4 acc[4][2];
#pragma unroll
  for (int i = 0; i < 4; ++i) {
    acc[i][0] = fz;
    acc[i][1] = fz;
  }
  const bf16x8* Ap = (const bf16x8*)As;
  const bf16x8* Bp = (const bf16x8*)Bs;
#pragma unroll
  for (int ks = 0; ks < 2; ++ks) {
    bf16x8 bfr[2];
#pragma unroll
    for (int ni = 0; ni < 2; ++ni)
      bfr[ni] = Bp[(wc + ni * 16 + lr) * 8 + ks * 4 + lg];
#pragma unroll
    for (int mi = 0; mi < 4; ++mi) {
      bf16x8 af = Ap[(mi * 16 + lr) * 8 + ks * 4 + lg];
      acc[mi][0] = mfma16(af, bfr[0], acc[mi][0]);
      acc[mi][1] = mfma16(af, bfr[1], acc[mi][1]);
    }
  }
#pragma unroll
  for (int ni = 0; ni < 2; ++ni) {
    const int col = d0 + wc + ni * 16 + lr;
    const float yv = y0[(size_t)b * 512 + col];
#pragma unroll
    for (int mi = 0; mi < 4; ++mi)
#pragma unroll
      for (int r = 0; r < 4; ++r) {
        const int m = mi * 16 + lg * 4 + r;
        X[((size_t)b * 64 + m) * 512 + col] = (bf16_t)(acc[mi][ni][r] + yv);
      }
  }
}

// traj[p, b, :] = Tmat[16x64] @ Ft[b] + y0[b,:]   (rows 10..15 are zero pad)
__global__ __launch_bounds__(256) void trajK(
    const bf16_t* __restrict__ Tm, const bf16_t* __restrict__ Ft,
    const float* __restrict__ y0, float* __restrict__ out) {
  __shared__ alignas(16) bf16_t As[16 * 64];
  __shared__ alignas(16) bf16_t Bs[128 * 64];
  const int tid = threadIdx.x, wid = tid >> 6, lane = tid & 63;
  const int lr = lane & 15, lg = lane >> 4;
  const int b = blockIdx.y;
  const int d0 = blockIdx.x * 128;
  {
    if (wid == 0) {
      const char* gT = (const char*)Tm;
      gload_lds16(gT + lane * 16, (char*)As);
      gload_lds16(gT + 1024 + lane * 16, (char*)As + 1024);
    }
    const char* gF = (const char*)(Ft + ((size_t)b * 512 + d0) * 64);
    for (int c = wid * 4; c < wid * 4 + 4; ++c)
      gload_lds16(gF + c * 1024 + lane * 16, (char*)Bs + c * 1024);
  }
  __syncthreads();
  const int wc = wid * 32;
  const f32x4 fz = {0.f, 0.f, 0.f, 0.f};
  f32x4 acc[2] = {fz, fz};
  const bf16x8* Ap = (const bf16x8*)As;
  const bf16x8* Bp = (const bf16x8*)Bs;
#pragma unroll
  for (int ks = 0; ks < 2; ++ks) {
    bf16x8 af = Ap[lr * 8 + ks * 4 + lg];
#pragma unroll
    for (int ni = 0; ni < 2; ++ni) {
      bf16x8 bfr = Bp[(wc + ni * 16 + lr) * 8 + ks * 4 + lg];
      acc[ni] = mfma16(af, bfr, acc[ni]);
    }
  }
#pragma unroll
  for (int ni = 0; ni < 2; ++ni) {
    const int col = d0 + wc + ni * 16 + lr;
    const float yv = y0[(size_t)b * 512 + col];
#pragma unroll
    for (int r = 0; r < 4; ++r) {
      const int p = lg * 4 + r;
      if (p < PT)
        out[(size_t)p * BATCH * DDIM + (size_t)b * DDIM + col] =
            acc[ni][r] + yv;
    }
  }
}

// ---------------------------------------------------------------------------
extern "C" void kernel_launch(void* const* d_in, const int* in_sizes, int n_in,
                              void* d_out, int out_size, void* d_ws,
                              size_t ws_size, hipStream_t stream) {
  (void)in_sizes; (void)n_in; (void)out_size;
  const float* y0 = (const float*)d_in[0];
  const float* tspan = (const float*)d_in[1];
  const float* W1 = (const float*)d_in[2];
  const float* b1 = (const float*)d_in[3];
  const float* W2 = (const float*)d_in[4];
  const float* b2 = (const float*)d_in[5];
  float* out = (float*)d_out;

  char* ws = (char*)d_ws;
  const size_t szW1t = (size_t)HDIM * DDIM * 2;
  const size_t szW2t = (size_t)DDIM * HDIM * 2;
  const size_t szK = 64 * 64 * 2;
  const size_t szT = 16 * 64 * 2;
  const size_t szX = (size_t)ROWS * DDIM * 2;
  const size_t szH = (size_t)ROWS * HDIM * 2;
  const size_t szF = (size_t)BATCH * DDIM * 64 * 2;
  if (ws_size < szW1t + szW2t + szK + szT + szX + szH + szF) return;

  bf16_t* W1t = (bf16_t*)ws; ws += szW1t;
  bf16_t* W2t = (bf16_t*)ws; ws += szW2t;
  bf16_t* Kmat = (bf16_t*)ws; ws += szK;
  bf16_t* Tmat = (bf16_t*)ws; ws += szT;
  bf16_t* X = (bf16_t*)ws; ws += szX;
  bf16_t* H = (bf16_t*)ws; ws += szH;
  bf16_t* Ft = (bf16_t*)ws; ws += szF;

  prep_matrices<<<1, 256, 0, stream>>>(tspan, Kmat, Tmat);
  transpose_bf16<<<dim3(HDIM / 32, DDIM / 32), dim3(32, 8), 0, stream>>>(
      W1, W1t, DDIM, HDIM);
  transpose_bf16<<<dim3(DDIM / 32, HDIM / 32), dim3(32, 8), 0, stream>>>(
      W2, W2t, HDIM, DDIM);
  init_X<<<(ROWS * DDIM) / 256, 256, 0, stream>>>(y0, X);

  for (int it = 0; it < NITER; ++it) {
    gemm_bt<true, false><<<dim3(HDIM / 128, ROWS / 128), 256, 0, stream>>>(
        X, W1t, b1, H, HDIM, DDIM);
    gemm_bt<false, true><<<dim3(DDIM / 128, ROWS / 128), 256, 0, stream>>>(
        H, W2t, b2, Ft, DDIM, HDIM);
    if (it < NITER - 1)
      evalK<<<dim3(DDIM / 128, BATCH), 256, 0, stream>>>(Kmat, Ft, y0, X);
  }
  trajK<<<dim3(DDIM / 128, BATCH), 256, 0, stream>>>(Tmat, Ft, y0, out);
}

// Round 2
// 1019.348 us; speedup vs baseline: 1.5216x; 1.5216x over previous
//
#include <hip/hip_runtime.h>

typedef __bf16 bf16_t;
typedef bf16_t bf16x8 __attribute__((ext_vector_type(8)));
typedef bf16_t bf16x4 __attribute__((ext_vector_type(4)));
typedef float  f32x4  __attribute__((ext_vector_type(4)));

#define DEVFN __device__ __forceinline__

constexpr int BATCH = 256;
constexpr int DDIM  = 512;
constexpr int HDIM  = 2048;
constexpr int MNODE = 64;
constexpr int NC    = 32;
constexpr int NITER = 12;
constexpr int PT    = 10;
constexpr int ROWS  = BATCH * MNODE;  // 16384

DEVFN float fast_tanh(float x) {
  float e = __builtin_amdgcn_exp2f(x * 2.8853900817779268f);
  return 1.0f - 2.0f * __builtin_amdgcn_rcpf(e + 1.0f);
}

DEVFN void gload_lds16(const void* g, void* l) {
  __builtin_amdgcn_global_load_lds(
      (__attribute__((address_space(1))) void*)(g),
      (__attribute__((address_space(3))) void*)(l), 16, 0, 0);
}

DEVFN f32x4 mfma16(bf16x8 a, bf16x8 b, f32x4 c) {
  return __builtin_amdgcn_mfma_f32_16x16x32_bf16(a, b, c, 0, 0, 0);
}

// Stage an R*256-thread-rounds tile (rows of 64 bf16 = 128B) into LDS with
// the st-style XOR swizzle baked into the GLOBAL source address (LDS dest
// stays linear, as global_load_lds requires).  g = tile origin, ldK = row
// stride in elements.
template <int R>
DEVFN void stage_tile(const bf16_t* g, int ldK, bf16_t* buf, int tid) {
#pragma unroll
  for (int j = 0; j < R; ++j) {
    const int t16 = j * 256 + tid;
    const int row = t16 >> 3;
    const int k = ((tid & 7) ^ (row & 7)) * 8;
    gload_lds16(g + (size_t)row * ldK + k, (char*)buf + t16 * 16);
  }
}

// Swizzled bf16x8 fragment read: row-major [rows][64] bf16 tile, 128B rows,
// 16B slot s holds global slot s ^ (row&7).
DEVFN bf16x8 frag(const bf16_t* buf, int row, int ks, int lg) {
  const int byte = row * 128 + ((ks * 64 + lg * 16) ^ ((row & 7) << 4));
  return *(const bf16x8*)((const char*)buf + byte);
}

// ---------------------------------------------------------------------------
// Prep: Kmat[64][64], Tmat[16][64] (bf16, plain row-major; swizzle applied at
// stage-address time).  X_next = Kmat @ F_b + y0 ; traj_p = Tmat @ F_b + y0.
// ---------------------------------------------------------------------------
__global__ __launch_bounds__(256) void prep_matrices(
    const float* __restrict__ tspan, bf16_t* __restrict__ Kmat,
    bf16_t* __restrict__ Tmat) {
  __shared__ float sphi[NC][MNODE];
  __shared__ float spsi[NC][MNODE];
  __shared__ float sA32[NC][NC];
  __shared__ float sAP[NC][MNODE];
  __shared__ float sphis[NC][PT];

  const int tid = threadIdx.x;
  const float t0 = tspan[0], t1 = tspan[PT - 1];
  const float half = 0.5f * (t1 - t0);
  const float pi = 3.14159265358979323846f;

  for (int i = tid; i < NC * MNODE; i += 256) {
    int n = i >> 6, m = i & 63;
    float th = pi * (float)m / 63.0f;
    float ph = cosf((float)n * th);
    sphi[n][m] = ph;
    float w = (m == 0 || m == 63) ? 0.5f : 1.0f;
    spsi[n][m] = ph * w * (2.0f / 63.0f) * (n == 0 ? 0.5f : 1.0f);
  }
  for (int i = tid; i < NC * NC; i += 256) {
    int j = i >> 5, q = i & 31;
    float v = 0.f;
    for (int k = 1; k < NC; ++k) {
      float dk = half / (2.0f * (float)k);
      float dval = 0.f;
      if (q == k - 1) dval += dk;
      if (q == k + 1) dval -= dk;
      float pj = (j == 0) ? ((k & 1) ? 1.0f : -1.0f) : ((j == k) ? 1.0f : 0.0f);
      v += pj * dval;
    }
    sA32[j][q] = v;
  }
  for (int i = tid; i < NC * PT; i += 256) {
    int n = i / PT, p = i % PT;
    float tau = -1.0f + 2.0f * (tspan[p] - t0) / (t1 - t0);
    tau = fminf(1.0f, fmaxf(-1.0f, tau));
    sphis[n][p] = cosf((float)n * acosf(tau));
  }
  __syncthreads();
  for (int i = tid; i < NC * MNODE; i += 256) {
    int n = i >> 6, m = i & 63;
    float v = 0.f;
    for (int q = 0; q < NC; ++q) v += sA32[n][q] * spsi[q][m];
    sAP[n][m] = v;
  }
  __syncthreads();
  for (int i = tid; i < MNODE * MNODE; i += 256) {
    int m = i >> 6, mp = i & 63;
    float v = 0.f;
    for (int n = 0; n < NC; ++n) v += sphi[n][m] * sAP[n][mp];
    Kmat[i] = (bf16_t)v;
  }
  for (int i = tid; i < 16 * MNODE; i += 256) {
    int p = i >> 6, mp = i & 63;
    float v = 0.f;
    if (p < PT) {
      for (int n = 0; n < NC; ++n) v += sphis[n][p] * sAP[n][mp];
    }
    Tmat[i] = (bf16_t)v;
  }
}

__global__ void transpose_bf16(const float* __restrict__ src,
                               bf16_t* __restrict__ dst, int R, int C) {
  __shared__ float tile[32][33];
  const int bx = blockIdx.x * 32, by = blockIdx.y * 32;
  const int tx = threadIdx.x, ty = threadIdx.y;
#pragma unroll
  for (int i = 0; i < 32; i += 8)
    tile[ty + i][tx] = src[(size_t)(by + ty + i) * C + (bx + tx)];
  __syncthreads();
#pragma unroll
  for (int i = 0; i < 32; i += 8)
    dst[(size_t)(bx + ty + i) * R + (by + tx)] = (bf16_t)tile[tx][ty + i];
}

__global__ void init_X(const float* __restrict__ y0, bf16_t* __restrict__ X) {
  size_t i = (size_t)blockIdx.x * 256 + threadIdx.x;
  int d = (int)(i & 511);
  int row = (int)(i >> 9);
  int b = row >> 6;
  X[i] = (bf16_t)y0[((size_t)b << 9) + d];
}

// ---------------------------------------------------------------------------
// Fused MFMA GEMM.  128x128 tile, BK=64, 4 waves, counted-vmcnt dbuf pipeline
// (stage k+1 first, vmcnt(8), raw barrier -> loads stay in flight across the
// compute phase), XOR-swizzled LDS (via pre-swizzled global source).
// FUSE=0: C = act(A @ Bt^T + bias)          (row-major bf16, TANH optional)
// FUSE=1: F = A@Bt^T+bias; X = Kmat@F + y0  (per-batch, written row-major)
// FUSE=2: F = A@Bt^T+bias; out = Tmat@F + y0 (f32 traj, rows p<10)
// ---------------------------------------------------------------------------
template <int TANH, int FUSE, int NXB, int KDIM>
__global__ __launch_bounds__(256, 2) void gemm_k(
    const bf16_t* __restrict__ A, const bf16_t* __restrict__ Bt,
    const float* __restrict__ bias, const bf16_t* __restrict__ KT,
    const float* __restrict__ y0, bf16_t* __restrict__ Cb,
    float* __restrict__ Cf) {
  constexpr int NC2 = NXB * 128;
  constexpr int nk = KDIM / 64;
  __shared__ alignas(16) char lds[FUSE ? 73728 : 65536];
  bf16_t* As = (bf16_t*)lds;               // 2 x 16KB (dbuf A)
  bf16_t* Bs = (bf16_t*)(lds + 32768);     // 2 x 16KB (dbuf B)
  bf16_t* KTs = (bf16_t*)(lds + 65536);    // 8KB Kmat / 2KB Tmat
  bf16_t* Fs = (bf16_t*)lds;               // 32KB, aliases As after K-loop

  const int tid = threadIdx.x;
  const int wid = tid >> 6, lane = tid & 63;
  const int lr = lane & 15, lg = lane >> 4;
  const int nwg = gridDim.x;
  const int id = blockIdx.x;
  const int swz = (id & 7) * (nwg >> 3) + (id >> 3);  // XCD-contiguous chunks
  const int bx = swz % NXB, by = swz / NXB;
  const int row0 = by * 128, col0 = bx * 128;
  const int wr = (wid >> 1) * 64, wc = (wid & 1) * 64;

  // ---- prologue: KT (oldest loads), then K-tile 0 ----
  if constexpr (FUSE == 1) stage_tile<2>(KT, 64, KTs, tid);
  if constexpr (FUSE == 2) {
    if (tid < 128) stage_tile<1>(KT, 64, KTs, tid);
  }
  const bf16_t* Ag = A + (size_t)row0 * KDIM;
  const bf16_t* Bg = Bt + (size_t)col0 * KDIM;
  stage_tile<4>(Ag, KDIM, As, tid);
  stage_tile<4>(Bg, KDIM, Bs, tid);

  const f32x4 fz = {0.f, 0.f, 0.f, 0.f};
  f32x4 acc[4][4];
#pragma unroll
  for (int i = 0; i < 4; ++i)
#pragma unroll
    for (int j = 0; j < 4; ++j) acc[i][j] = fz;

  for (int kt = 0; kt < nk; ++kt) {
    const int cur = kt & 1;
    if (kt + 1 < nk) {
      stage_tile<4>(Ag + (kt + 1) * 64, KDIM, As + (cur ^ 1) * 8192, tid);
      stage_tile<4>(Bg + (kt + 1) * 64, KDIM, Bs + (cur ^ 1) * 8192, tid);
      asm volatile("s_waitcnt vmcnt(8)" ::: "memory");  // tile kt ready
    } else {
      asm volatile("s_waitcnt vmcnt(0)" ::: "memory");
    }
    __builtin_amdgcn_s_barrier();
    __builtin_amdgcn_sched_barrier(0);
    const bf16_t* Ab = As + cur * 8192;
    const bf16_t* Bb = Bs + cur * 8192;
#pragma unroll
    for (int ks = 0; ks < 2; ++ks) {
      bf16x8 af[4], bfv[4];
#pragma unroll
      for (int mi = 0; mi < 4; ++mi)
        af[mi] = frag(Ab, wr + mi * 16 + lr, ks, lg);
#pragma unroll
      for (int ni = 0; ni < 4; ++ni)
        bfv[ni] = frag(Bb, wc + ni * 16 + lr, ks, lg);
#pragma unroll
      for (int mi = 0; mi < 4; ++mi)
#pragma unroll
        for (int ni = 0; ni < 4; ++ni)
          acc[mi][ni] = mfma16(af[mi], bfv[ni], acc[mi][ni]);
    }
    __builtin_amdgcn_sched_barrier(0);
    __builtin_amdgcn_s_barrier();  // reads done before next stage overwrites
  }

  if constexpr (FUSE == 0) {
#pragma unroll
    for (int ni = 0; ni < 4; ++ni) {
      const int col = col0 + wc + ni * 16 + lr;
      const float bv = bias[col];
#pragma unroll
      for (int mi = 0; mi < 4; ++mi) {
        const int row = row0 + wr + mi * 16 + lg * 4;
#pragma unroll
        for (int r = 0; r < 4; ++r) {
          float v = acc[mi][ni][r] + bv;
          if constexpr (TANH) v = fast_tanh(v);
          Cb[(size_t)(row + r) * NC2 + col] = (bf16_t)v;
        }
      }
    }
  } else {
    // F -> LDS, layout [batch_loc(2)][d_local(128)][m(64)], XOR-swizzled rows
#pragma unroll
    for (int ni = 0; ni < 4; ++ni) {
      const int col = col0 + wc + ni * 16 + lr;
      const float bv = bias[col];
      const int fr = (wr >> 6) * 128 + wc + ni * 16 + lr;
#pragma unroll
      for (int mi = 0; mi < 4; ++mi) {
        const int m0 = mi * 16 + lg * 4;
        bf16x4 pack;
#pragma unroll
        for (int r = 0; r < 4; ++r) pack[r] = (bf16_t)(acc[mi][ni][r] + bv);
        *(bf16x4*)((char*)Fs + fr * 128 + ((m0 * 2) ^ ((fr & 7) << 4))) = pack;
      }
    }
    __syncthreads();

    const int b = (row0 >> 6) + (wr >> 6);  // global batch of this wave
    constexpr int MI2 = (FUSE == 1) ? 4 : 1;
    f32x4 acc2[MI2][4];
#pragma unroll
    for (int mi = 0; mi < MI2; ++mi)
#pragma unroll
      for (int ni = 0; ni < 4; ++ni) acc2[mi][ni] = fz;
#pragma unroll
    for (int ks = 0; ks < 2; ++ks) {
      bf16x8 bf2[4];
#pragma unroll
      for (int ni = 0; ni < 4; ++ni)
        bf2[ni] = frag(Fs, (wr >> 6) * 128 + wc + ni * 16 + lr, ks, lg);
#pragma unroll
      for (int mi = 0; mi < MI2; ++mi) {
        bf16x8 afk = frag(KTs, mi * 16 + lr, ks, lg);
#pragma unroll
        for (int ni = 0; ni < 4; ++ni)
          acc2[mi][ni] = mfma16(afk, bf2[ni], acc2[mi][ni]);
      }
    }
#pragma unroll
    for (int ni = 0; ni < 4; ++ni) {
      const int dg = col0 + wc + ni * 16 + lr;
      const float yv = y0[(size_t)b * DDIM + dg];
      if constexpr (FUSE == 1) {
#pragma unroll
        for (int mi = 0; mi < 4; ++mi)
#pragma unroll
          for (int r = 0; r < 4; ++r) {
            const int m = mi * 16 + lg * 4 + r;
            Cb[((size_t)b * 64 + m) * DDIM + dg] = (bf16_t)(acc2[mi][ni][r] + yv);
          }
      } else {
#pragma unroll
        for (int r = 0; r < 4; ++r) {
          const int p = lg * 4 + r;
          if (p < PT)
            Cf[(size_t)p * BATCH * DDIM + (size_t)b * DDIM + dg] =
                acc2[0][ni][r] + yv;
        }
      }
    }
  }
}

// ---------------------------------------------------------------------------
extern "C" void kernel_launch(void* const* d_in, const int* in_sizes, int n_in,
                              void* d_out, int out_size, void* d_ws,
                              size_t ws_size, hipStream_t stream) {
  (void)in_sizes; (void)n_in; (void)out_size;
  const float* y0 = (const float*)d_in[0];
  const float* tspan = (const float*)d_in[1];
  const float* W1 = (const float*)d_in[2];
  const float* b1 = (const float*)d_in[3];
  const float* W2 = (const float*)d_in[4];
  const float* b2 = (const float*)d_in[5];
  float* out = (float*)d_out;

  char* ws = (char*)d_ws;
  const size_t szW1t = (size_t)HDIM * DDIM * 2;
  const size_t szW2t = (size_t)DDIM * HDIM * 2;
  const size_t szK = 64 * 64 * 2;
  const size_t szT = 16 * 64 * 2;
  const size_t szX = (size_t)ROWS * DDIM * 2;
  const size_t szH = (size_t)ROWS * HDIM * 2;
  if (ws_size < szW1t + szW2t + szK + szT + szX + szH) return;

  bf16_t* W1t = (bf16_t*)ws; ws += szW1t;
  bf16_t* W2t = (bf16_t*)ws; ws += szW2t;
  bf16_t* Kmat = (bf16_t*)ws; ws += szK;
  bf16_t* Tmat = (bf16_t*)ws; ws += szT;
  bf16_t* X = (bf16_t*)ws; ws += szX;
  bf16_t* H = (bf16_t*)ws; ws += szH;

  prep_matrices<<<1, 256, 0, stream>>>(tspan, Kmat, Tmat);
  transpose_bf16<<<dim3(HDIM / 32, DDIM / 32), dim3(32, 8), 0, stream>>>(
      W1, W1t, DDIM, HDIM);
  transpose_bf16<<<dim3(DDIM / 32, HDIM / 32), dim3(32, 8), 0, stream>>>(
      W2, W2t, HDIM, DDIM);
  init_X<<<(ROWS * DDIM) / 256, 256, 0, stream>>>(y0, X);

  for (int it = 0; it < NITER; ++it) {
    gemm_k<1, 0, 16, 512><<<2048, 256, 0, stream>>>(
        X, W1t, b1, nullptr, nullptr, H, nullptr);
    if (it < NITER - 1)
      gemm_k<0, 1, 4, 2048><<<512, 256, 0, stream>>>(
          H, W2t, b2, Kmat, y0, X, nullptr);
    else
      gemm_k<0, 2, 4, 2048><<<512, 256, 0, stream>>>(
          H, W2t, b2, Tmat, y0, nullptr, out);
  }
}